// Round 12
// baseline (470.552 us; speedup 1.0000x reference)
//
#include <hip/hip_runtime.h>
#include <stdint.h>

typedef __attribute__((ext_vector_type(8))) short bf16x8;
typedef __attribute__((ext_vector_type(4))) float f32x4;
typedef __attribute__((ext_vector_type(16))) float f32x16;
typedef unsigned short u16;
typedef unsigned int   u32;
typedef unsigned long long u64;

#define S_LEN 2048
#define NH    16
#define NKV   4
#define DH    128
#define DM    2048
#define QKV_N 3072
#define MROWS 4096   // B*S

__device__ __forceinline__ u16 f2bf(float x) {
  u32 u = __float_as_uint(x);
  return (u16)((u + 0x7fffu + ((u >> 16) & 1u)) >> 16);   // RNE
}
__device__ __forceinline__ float bf2f(u16 h) {
  return __uint_as_float(((u32)h) << 16);
}
__device__ __forceinline__ u32 cvtpk(float lo, float hi) {   // T12: 1 instr vs ~8 VALU
  u32 r;
  asm("v_cvt_pk_bf16_f32 %0, %1, %2" : "=v"(r) : "v"(lo), "v"(hi));
  return r;
}
__device__ __forceinline__ void plswap(u32& a, u32& b) {     // lane halves swap
  asm volatile("v_permlane32_swap_b32 %0, %1" : "+v"(a), "+v"(b));
}
__device__ __forceinline__ void gload_lds16(const void* g, void* l) {
  __builtin_amdgcn_global_load_lds((const __attribute__((address_space(1))) void*)g,
                                   (__attribute__((address_space(3))) void*)l, 16, 0, 0);
}

// ---------------- f32 -> bf16 convert (vectorized, G13) ----------------
__global__ void __launch_bounds__(256) convert_x_kernel(const float* __restrict__ x,
                                                        u16* __restrict__ o) {
  int idx = (blockIdx.x * 256 + threadIdx.x) * 8;
  float4 a = *(const float4*)(x + idx);
  float4 b = *(const float4*)(x + idx + 4);
  union { u16 s[8]; uint4 v; } t;
  t.s[0] = f2bf(a.x); t.s[1] = f2bf(a.y); t.s[2] = f2bf(a.z); t.s[3] = f2bf(a.w);
  t.s[4] = f2bf(b.x); t.s[5] = f2bf(b.y); t.s[6] = f2bf(b.z); t.s[7] = f2bf(b.w);
  *(uint4*)(o + idx) = t.v;
}

// ------------- W [2048][N] f32  ->  Wt [N][2048] bf16 (LDS tiled) -------------
__global__ void __launch_bounds__(256) transpose_w_kernel(const float* __restrict__ src,
                                                          u16* __restrict__ dst, int N) {
  __shared__ float t[64][65];
  const int bx = blockIdx.x, by = blockIdx.y, tid = threadIdx.x;
#pragma unroll
  for (int rep = 0; rep < 16; ++rep) {
    int lin = rep * 256 + tid;
    int i = lin >> 6, jj = lin & 63;                 // i = k-local, jj = n-local
    t[i][jj] = src[(size_t)(bx * 64 + i) * N + by * 64 + jj];
  }
  __syncthreads();
#pragma unroll
  for (int rep = 0; rep < 16; ++rep) {
    int lin = rep * 256 + tid;
    int nr = lin >> 6, kc = lin & 63;
    dst[(size_t)(by * 64 + nr) * DM + bx * 64 + kc] = f2bf(t[kc][nr]);
  }
}

// ------------- RoPE tables: ctab/stab[s*64 + i] -------------
__global__ void __launch_bounds__(256) rope_tables_kernel(float* __restrict__ ct,
                                                          float* __restrict__ st_) {
  int idx = blockIdx.x * 256 + threadIdx.x;          // 2048*64
  int s = idx >> 6, i = idx & 63;
  const float L2_10000 = 13.287712379549449f;
  float freq = exp2f(-(float)i * (1.0f / 64.0f) * L2_10000);
  float ang = (float)s * freq;
  ct[idx] = cosf(ang);
  st_[idx] = sinf(ang);
}

// ------------- GEMM: C[M][N] = A[M][K](bf16) * Bt[N][K](bf16)^T  (m97 structure) -------------
template <int OUTF32>
__global__ void __launch_bounds__(256) gemm_bt(const u16* __restrict__ A,
                                               const u16* __restrict__ Bt,
                                               void* __restrict__ C,
                                               int M, int N, int K) {
  __shared__ __align__(16) u16 As[128 * 32];
  __shared__ __align__(16) u16 Bs[128 * 32];
  const int tid = threadIdx.x;
  const int w = tid >> 6, l = tid & 63;
  const int g = l >> 4, q15 = l & 15;
  const int row0 = blockIdx.y * 128, col0 = blockIdx.x * 128;
  const int wm = (w >> 1) * 64, wn = (w & 1) * 64;
  const f32x4 fz = {0.f, 0.f, 0.f, 0.f};
  f32x4 acc[4][4];
#pragma unroll
  for (int m = 0; m < 4; ++m)
#pragma unroll
    for (int n = 0; n < 4; ++n) acc[m][n] = fz;

  for (int kt = 0; kt < K; kt += 32) {
#pragma unroll
    for (int c = 0; c < 2; ++c) {
      int P = (w * 2 + c) * 1024;
      int Pl = P + l * 16;
      int arow = Pl >> 6, acolb = Pl & 63;          // 64B per 32-elem row
      gload_lds16((const char*)A + ((size_t)(row0 + arow) * K + kt) * 2 + acolb,
                  (char*)As + P);
      gload_lds16((const char*)Bt + ((size_t)(col0 + arow) * K + kt) * 2 + acolb,
                  (char*)Bs + P);
    }
    __syncthreads();
    bf16x8 af[4], bfv[4];
#pragma unroll
    for (int m = 0; m < 4; ++m)
      af[m] = *(const bf16x8*)((const char*)As + (wm + m * 16 + q15) * 64 + g * 16);
#pragma unroll
    for (int n = 0; n < 4; ++n)
      bfv[n] = *(const bf16x8*)((const char*)Bs + (wn + n * 16 + q15) * 64 + g * 16);
#pragma unroll
    for (int m = 0; m < 4; ++m)
#pragma unroll
      for (int n = 0; n < 4; ++n)
        acc[m][n] = __builtin_amdgcn_mfma_f32_16x16x32_bf16(af[m], bfv[n], acc[m][n], 0, 0, 0);
    __syncthreads();
  }
#pragma unroll
  for (int m = 0; m < 4; ++m)
#pragma unroll
    for (int n = 0; n < 4; ++n)
#pragma unroll
      for (int r = 0; r < 4; ++r) {
        int rr = row0 + wm + m * 16 + g * 4 + r;    // C/D: row=(l>>4)*4+reg
        int cc = col0 + wn + n * 16 + q15;          //      col=l&15
        float v = acc[m][n][r];
        if (OUTF32) ((float*)C)[(size_t)rr * N + cc] = v;
        else        ((u16*)C)[(size_t)rr * N + cc]  = f2bf(v);
      }
}

// ------------- fused RMSNorm + RoPE; one wave per (row, head-job) -------------
// jobs 0..15 = q heads (pre-scaled by 1/sqrt(DH)), 16..19 = k heads
__global__ void __launch_bounds__(256) norm_rope_kernel(const u16* __restrict__ qkv,
                                                        const float* __restrict__ qw,
                                                        const float* __restrict__ kw,
                                                        const float* __restrict__ ct,
                                                        const float* __restrict__ st_,
                                                        u16* __restrict__ Qo,
                                                        u16* __restrict__ Ko) {
  int wid = blockIdx.x * 4 + (threadIdx.x >> 6);
  int l = threadIdx.x & 63;
  int row = wid / 20;
  int j = wid - row * 20;
  int b = row >> 11, s = row & 2047;
  bool isq = j < 16;
  int h = isq ? j : (j - 16);
  const u16* src = qkv + (size_t)row * QKV_N + (isq ? h * DH : (2048 + h * DH));
  float x1 = bf2f(src[l]), x2 = bf2f(src[l + 64]);
  float ss = x1 * x1 + x2 * x2;
#pragma unroll
  for (int off = 32; off > 0; off >>= 1) ss += __shfl_xor(ss, off);
  float rn = rsqrtf(ss * (1.0f / 128.0f) + 1e-6f);
  const float* wv = isq ? qw : kw;
  float n1 = x1 * rn * wv[l], n2 = x2 * rn * wv[l + 64];
  float cv = ct[s * 64 + l], sv = st_[s * 64 + l];
  float o1 = n1 * cv - n2 * sv;
  float o2 = n2 * cv + n1 * sv;
  float scale = isq ? 0.08838834764831845f : 1.0f;   // 1/sqrt(128) folded into Q
  u16* dst = isq ? (Qo + ((size_t)(b * NH + h) * S_LEN + s) * DH)
                 : (Ko + ((size_t)(b * NKV + h) * S_LEN + s) * DH);
  dst[l]      = f2bf(o1 * scale);
  dst[l + 64] = f2bf(o2 * scale);
}

// ------------- V transpose: qkv[...,2560+h*128+d] -> vt[(b*4+h)*128+d][S] -------------
__global__ void __launch_bounds__(256) vtrans_kernel(const u16* __restrict__ qkv,
                                                     u16* __restrict__ vt) {
  __shared__ u16 t[64][65];
  const int st = blockIdx.x, dt = blockIdx.y, bz = blockIdx.z;  // bz = b*4+h
  const int tid = threadIdx.x;
#pragma unroll
  for (int rep = 0; rep < 16; ++rep) {
    int lin = rep * 256 + tid;
    int i = lin >> 6, jj = lin & 63;                // i = s-local, jj = d-local
    t[i][jj] = qkv[(size_t)((bz >> 2) * S_LEN + st * 64 + i) * QKV_N
                   + 2560 + (bz & 3) * DH + dt * 64 + jj];
  }
  __syncthreads();
#pragma unroll
  for (int rep = 0; rep < 16; ++rep) {
    int lin = rep * 256 + tid;
    int dr = lin >> 6, sc = lin & 63;
    vt[((size_t)bz * DH + dt * 64 + dr) * S_LEN + st * 64 + sc] = t[sc][dr];
  }
}

// ------------- flash attention, 32x32 swapped-QK core + SPLIT-K (flash-decoding) -------------
// R11 post-mortem: grid=256 -> 1 block/CU -> 1 wave/SIMD -> every latency exposed (counted
// vmcnt was null; all pipes <30%). Fix: split each (pair,head)'s kv range into two halves ->
// 512 blocks x EXACTLY 17 iterations, 2 blocks/CU (128KB LDS), 2 waves/SIMD.
//   pass tq: half0 = kv tiles [0,tq], half1 = [tq+1, 2tq+1]; per-block total = 17 both halves.
// Each half stores an UNNORMALIZED partial (O_acc bf16 -> d_out region, m/l f32 -> wqkvt
// region; both dead during attn); second-finishing block (threadfence + atomicAdd handshake)
// combines both bf16 partials (order-independent => deterministic) and writes attn out.
// Mask fill -3e38 (not -1e30): a fully-masked first tile then yields p=exp(-3e38+1e30)=0,
// not exp(0)=1 (pr=0 half1 case). Core unchanged from R9-R11 (verified): 32x32 swapped QK^T,
// in-lane softmax, cvt_pk+permlane32_swap, O^T=mfma(V^T,P^T), defer-max, setprio, XOR swizzles.
// Block id: [2:0]=(b,kvh) XCD-affine, [4:3]=q-head, [7:5]=pair pr, [8]=half.
__global__ void __launch_bounds__(256, 2) attn_kernel(const u16* __restrict__ Qg,
                                                      const u16* __restrict__ Kg,
                                                      const u16* __restrict__ Vt,
                                                      u16* __restrict__ partO,
                                                      float* __restrict__ mlbuf,
                                                      u32* __restrict__ flags,
                                                      u16* __restrict__ Oout) {
  __shared__ __align__(16) char smem[65536];   // [2][ K:16KB | V:16KB ]
  __shared__ u32 who;
  const int tid = threadIdx.x;
  const int w = tid >> 6, l = tid & 63;        // w = 0..3
  const int q31 = l & 31, hi = l >> 5;
  const int id = blockIdx.x;
  const int grp = id & 7;                      // b*4 + kvh
  const int mem = (id >> 3) & 3;               // q-head within kv group
  const int pr  = (id >> 5) & 7;               // pair index 0..7
  const int hf  = id >> 8;                     // kv half 0/1
  const int b   = grp >> 2, kvh = grp & 3;
  const int h   = kvh * 4 + mem;

  const char* Kbase = (const char*)(Kg + (size_t)(b * NKV + kvh) * S_LEN * DH);
  const char* Vbase = (const char*)(Vt + (size_t)(b * NKV + kvh) * DH * S_LEN);

  // stage KV tile kt into buffer `buf`: 8 gload_lds per wave (4 x {K,V}).
  auto stage = [&](int buf, int kt) {
    char* Ksb = smem + buf * 32768;
    char* Vsb = Ksb + 16384;
    const char* Kt  = Kbase + (size_t)kt * 64 * 256;
    const char* Vtb = Vbase + (size_t)kt * 128;
#pragma unroll
    for (int i = 0; i < 4; ++i) {
      int off = w * 4096 + i * 1024 + l * 16;
      int row = off >> 8;
      { // K: [64 kv][128 d] bf16, rows 256B, XOR (row&15)<<4
        int cb = (off & 255) ^ ((row & 15) << 4);
        gload_lds16(Kt + (size_t)row * 256 + cb, Ksb + off); }
      { // V: d-paired rows: row=d>>1, byte7=d&1, low 7 bits = kv*2
        int qoff = (off & 255) ^ ((row & 15) << 4);
        int d = row * 2 + (qoff >> 7);
        int kvb = qoff & 127;
        gload_lds16(Vtb + (size_t)d * (S_LEN * 2) + kvb, Vsb + off); }
    }
  };

  stage(0, hf ? (pr + 1) : 0);    // first tile of pass 0 for this half
  int cur = 0;

  for (int pass = 0; pass < 2; ++pass) {
    const int tq   = pass ? (15 - pr) : pr;
    const int kbeg = pass ? (hf ? (16 - pr) : 0) : (hf ? (pr + 1) : 0);
    const int kend = pass ? (hf ? (31 - 2 * pr) : (15 - pr)) : (hf ? (2 * pr + 1) : pr);
    const int loB  = hf ? (16 - pr) : 0;       // pass 1's first tile (for cross-pass prefetch)
    const int qb   = tq * 128;
    const int qg   = qb + w * 32 + q31;        // lane's q row

    // Q row in registers: lane l&31 owns row qg; chunk c covers d = c*16 + hi*8 .. +7
    bf16x8 qreg[8];
    const u16* Qrow = Qg + ((size_t)(b * NH + h) * S_LEN + qg) * DH;
#pragma unroll
    for (int c = 0; c < 8; ++c)
      qreg[c] = *(const bf16x8*)(Qrow + c * 16 + hi * 8);

    f32x16 acc[4];
#pragma unroll
    for (int dt = 0; dt < 4; ++dt)
#pragma unroll
      for (int r = 0; r < 16; ++r) acc[dt][r] = 0.f;
    float mrun = -1e30f, lrun = 0.f;

    for (int kt = kbeg; kt <= kend; ++kt) {
      // counted vmcnt (T4): issue next stage, wait only for the PREVIOUS tile's 8 loads.
      if (kt < kend) {
        stage(cur ^ 1, kt + 1);
        asm volatile("s_waitcnt vmcnt(8)" ::: "memory");
      } else if (pass == 0) {
        stage(cur ^ 1, loB);
        asm volatile("s_waitcnt vmcnt(8)" ::: "memory");
      } else {
        asm volatile("s_waitcnt vmcnt(0)" ::: "memory");   // final tile only
      }
      __builtin_amdgcn_sched_barrier(0);       // rule 18: pin the wait
      __builtin_amdgcn_s_barrier();            // all waves' cur-tile writes visible

      const char* Ks = smem + cur * 32768;
      const char* Vs = Ks + 16384;

      // QK^T swapped: sa[s] = K[s-subtile] * Q^T -> P^T tile [32 kv][32 q]
      f32x16 sa[2];
#pragma unroll
      for (int s = 0; s < 2; ++s)
#pragma unroll
        for (int r = 0; r < 16; ++r) sa[s][r] = 0.f;
      __builtin_amdgcn_s_setprio(1);
#pragma unroll
      for (int s = 0; s < 2; ++s) {
        int krow = s * 32 + q31;
        const char* kr = Ks + krow * 256;
        int sw = (krow & 15) << 4;
#pragma unroll
        for (int c = 0; c < 8; ++c) {
          bf16x8 kf = *(const bf16x8*)(kr + ((c * 32 + hi * 16) ^ sw));
          sa[s] = __builtin_amdgcn_mfma_f32_32x32x16_bf16(kf, qreg[c], sa[s], 0, 0, 0);
        }
      }
      __builtin_amdgcn_s_setprio(0);

      // masking + in-lane max (bound kt*64+63 vs warp base — R8 lesson).
      // fill = -3e38 so a fully-masked row with mrun still -1e30 gets p = exp(-3e38+1e30) = 0.
      const bool domask = (kt * 64 + 63) > (qb + w * 32);
      float tmax = -1e30f;
#pragma unroll
      for (int s = 0; s < 2; ++s)
#pragma unroll
        for (int r = 0; r < 16; ++r) {
          float v = sa[s][r];
          if (domask) {
            int kvg = kt * 64 + s * 32 + (r & 3) + 8 * (r >> 2) + 4 * hi;
            if (kvg > qg) v = -3.0e38f;
          }
          sa[s][r] = v;
          tmax = fmaxf(tmax, v);
        }
      tmax = fmaxf(tmax, __shfl_xor(tmax, 32));

      const bool defer = __all(tmax <= mrun + 8.0f);  // T13 (wave-uniform)
      const float mnew = defer ? mrun : fmaxf(mrun, tmax);

      // exp + pack to PV B-frags: pfrag[ks] = P[q=l&31][kv = ks*16 + hi*8 + (0..7)]
      float tsum = 0.f;
      union { u32 u[4]; bf16x8 v; } pf[4];
#pragma unroll
      for (int s = 0; s < 2; ++s)
#pragma unroll
        for (int kl = 0; kl < 2; ++kl) {
          float e0 = __expf(sa[s][kl * 8 + 0] - mnew);
          float e1 = __expf(sa[s][kl * 8 + 1] - mnew);
          float e2 = __expf(sa[s][kl * 8 + 2] - mnew);
          float e3 = __expf(sa[s][kl * 8 + 3] - mnew);
          float e4 = __expf(sa[s][kl * 8 + 4] - mnew);
          float e5 = __expf(sa[s][kl * 8 + 5] - mnew);
          float e6 = __expf(sa[s][kl * 8 + 6] - mnew);
          float e7 = __expf(sa[s][kl * 8 + 7] - mnew);
          tsum += (e0 + e1) + (e2 + e3) + (e4 + e5) + (e6 + e7);
          u32 A0 = cvtpk(e0, e1), A1 = cvtpk(e2, e3);
          u32 B0 = cvtpk(e4, e5), B1 = cvtpk(e6, e7);
          plswap(A0, B0);   // -> word0 / word2
          plswap(A1, B1);   // -> word1 / word3
          int ks = s * 2 + kl;
          pf[ks].u[0] = A0; pf[ks].u[1] = A1; pf[ks].u[2] = B0; pf[ks].u[3] = B1;
        }
      tsum += __shfl_xor(tsum, 32);

      if (defer) {
        lrun += tsum;
      } else {
        float alpha = __expf(mrun - mnew);
        lrun = lrun * alpha + tsum;
        mrun = mnew;
#pragma unroll
        for (int dt = 0; dt < 4; ++dt)
#pragma unroll
          for (int r = 0; r < 16; ++r) acc[dt][r] *= alpha;   // lane-local (col = q)
      }

      // PV: acc[dt] += V^T-frag(dt,ks) * pfrag[ks]  -> O^T[d][q]
      __builtin_amdgcn_s_setprio(1);
#pragma unroll
      for (int dt = 0; dt < 4; ++dt) {
        int d = dt * 32 + q31;
        int vrow = d >> 1;
        const char* vr = Vs + vrow * 256;
        int sw = (vrow & 15) << 4;
        int hb = (d & 1) << 7;
#pragma unroll
        for (int ks = 0; ks < 4; ++ks) {
          bf16x8 vf = *(const bf16x8*)(vr + ((hb | (ks * 32 + hi * 16)) ^ sw));
          acc[dt] = __builtin_amdgcn_mfma_f32_32x32x16_bf16(vf, pf[ks].v, acc[dt], 0, 0, 0);
        }
      }
      __builtin_amdgcn_s_setprio(0);

      __builtin_amdgcn_s_barrier();   // WAR guard: everyone done reading cur
      cur ^= 1;
    }

    // ---- store unnormalized partial (bf16 O_acc, f32 m/l) ----
    size_t prow = (size_t)(b * NH + h) * S_LEN + qg;
    u16* Pb = partO + ((size_t)hf * 65536 + prow) * 128;
#pragma unroll
    for (int dt = 0; dt < 4; ++dt)
#pragma unroll
      for (int rg = 0; rg < 4; ++rg) {
        int d0 = dt * 32 + rg * 8 + hi * 4;
        u32 w0 = cvtpk(acc[dt][rg * 4 + 0], acc[dt][rg * 4 + 1]);
        u32 w1 = cvtpk(acc[dt][rg * 4 + 2], acc[dt][rg * 4 + 3]);
        *(u64*)(Pb + d0) = (u64)w0 | ((u64)w1 << 32);
      }
    if (hi == 0) {
      float2 ml; ml.x = mrun; ml.y = lrun;
      *(float2*)(mlbuf + ((size_t)hf * 65536 + prow) * 2) = ml;
    }
    __threadfence();                 // release: partials visible device-wide
    __syncthreads();
    if (tid == 0) who = atomicAdd(&flags[(b * NH + h) * 16 + tq], 1u);
    __syncthreads();

    if (who == 1) {                  // we finished second -> combine both halves
      __threadfence();               // acquire partner's stores
      int r  = tid >> 1;             // 0..127 (row within tile)
      int cg = (tid & 1) * 64;       // col half
      size_t rowi = (size_t)(b * NH + h) * S_LEN + qb + r;
      const u16* P0 = partO + rowi * 128;
      const u16* P1 = partO + ((size_t)65536 + rowi) * 128;
      float2 ml0 = *(const float2*)(mlbuf + rowi * 2);
      float2 ml1 = *(const float2*)(mlbuf + ((size_t)65536 + rowi) * 2);
      float ms = fmaxf(ml0.x, ml1.x);
      float w0 = __expf(ml0.x - ms), w1 = __expf(ml1.x - ms);
      float dn = 1.0f / (ml0.y * w0 + ml1.y * w1);
      u16* Ob = Oout + ((size_t)b * S_LEN + qb + r) * DM + h * DH + cg;
#pragma unroll
      for (int j = 0; j < 64; j += 4) {
        u64 a0 = *(const u64*)(P0 + cg + j);
        u64 a1 = *(const u64*)(P1 + cg + j);
        float f0 = bf2f((u16)(a0 >> 0))  * w0 + bf2f((u16)(a1 >> 0))  * w1;
        float f1 = bf2f((u16)(a0 >> 16)) * w0 + bf2f((u16)(a1 >> 16)) * w1;
        float f2 = bf2f((u16)(a0 >> 32)) * w0 + bf2f((u16)(a1 >> 32)) * w1;
        float f3 = bf2f((u16)(a0 >> 48)) * w0 + bf2f((u16)(a1 >> 48)) * w1;
        u32 o0 = cvtpk(f0 * dn, f1 * dn);
        u32 o1 = cvtpk(f2 * dn, f3 * dn);
        *(u64*)(Ob + j) = (u64)o0 | ((u64)o1 << 32);
      }
    }
  }
}

extern "C" void kernel_launch(void* const* d_in, const int* in_sizes, int n_in,
                              void* d_out, int out_size, void* d_ws, size_t ws_size,
                              hipStream_t stream) {
  (void)in_sizes; (void)n_in; (void)out_size; (void)ws_size;
  const float* x  = (const float*)d_in[0];
  const float* Wq = (const float*)d_in[1];
  const float* Wk = (const float*)d_in[2];
  const float* Wv = (const float*)d_in[3];
  const float* Wo = (const float*)d_in[4];
  const float* qw = (const float*)d_in[5];
  const float* kw = (const float*)d_in[6];

  char* ws = (char*)d_ws;
  // ws layout (~64 MB). During attn: xb, wqkvt, qkvp(d_out) are dead -> reused for
  // attn output, m/l partials, and bf16 O partials respectively.
  u16*   xb    = (u16*)(ws + 0);                       // 16.8 MB [4096][2048]
  u16*   wqkvt = (u16*)(ws + 16777216);                // 12.6 MB [3072][2048]
  u16*   wot   = (u16*)(ws + 29360128);                //  8.4 MB [2048][2048]
  u16*   qo    = (u16*)(ws + 37748736);                // 16.8 MB [B][16][S][128]
  u16*   ko    = (u16*)(ws + 54525952);                //  4.2 MB [B][4][S][128]
  u16*   vt    = (u16*)(ws + 58720256);                //  4.2 MB [B][4][128][S]
  float* ctab  = (float*)(ws + 62914560);              //  0.5 MB
  float* stab  = (float*)(ws + 63438848);              //  0.5 MB
  u32*   flags = (u32*)(ws + 63963136);                //  2 KB (512 flags)
  u16*   qkvp  = (u16*)d_out;                          // 25.2 MB staged in d_out
  u16*   attn  = (u16*)(ws + 0);                       // aliases xb
  u16*   partO = (u16*)d_out;                          // 33.5 MB partials (qkv dead by then)
  float* mlbuf = (float*)(ws + 16777216);              //  1 MB partial m/l (aliases wqkvt)
  float* outp  = (float*)d_out;

  hipMemsetAsync(flags, 0, 2048, stream);              // zero handshake flags every launch

  convert_x_kernel<<<4096, 256, 0, stream>>>(x, xb);
  transpose_w_kernel<<<dim3(32, 32), 256, 0, stream>>>(Wq, wqkvt, 2048);
  transpose_w_kernel<<<dim3(32, 8),  256, 0, stream>>>(Wk, wqkvt + (size_t)2048 * 2048, 512);
  transpose_w_kernel<<<dim3(32, 8),  256, 0, stream>>>(Wv, wqkvt + (size_t)2560 * 2048, 512);
  transpose_w_kernel<<<dim3(32, 32), 256, 0, stream>>>(Wo, wot, 2048);
  rope_tables_kernel<<<512, 256, 0, stream>>>(ctab, stab);

  gemm_bt<0><<<dim3(24, 32), 256, 0, stream>>>(xb, wqkvt, qkvp, MROWS, QKV_N, DM);
  norm_rope_kernel<<<20480, 256, 0, stream>>>(qkvp, qw, kw, ctab, stab, qo, ko);
  vtrans_kernel<<<dim3(32, 2, 8), 256, 0, stream>>>(qkvp, vt);
  attn_kernel<<<512, 256, 0, stream>>>(qo, ko, vt, partO, mlbuf, flags, attn);
  gemm_bt<1><<<dim3(16, 32), 256, 0, stream>>>(attn, wot, outp, MROWS, DM, DM);
}

// Round 13
// 230.913 us; speedup vs baseline: 2.0378x; 2.0378x over previous
//
#include <hip/hip_runtime.h>
#include <stdint.h>

typedef __attribute__((ext_vector_type(8))) short bf16x8;
typedef __attribute__((ext_vector_type(4))) float f32x4;
typedef __attribute__((ext_vector_type(16))) float f32x16;
typedef unsigned short u16;
typedef unsigned int   u32;
typedef unsigned long long u64;

#define S_LEN 2048
#define NH    16
#define NKV   4
#define DH    128
#define DM    2048
#define QKV_N 3072
#define MROWS 4096   // B*S

__device__ __forceinline__ u16 f2bf(float x) {
  u32 u = __float_as_uint(x);
  return (u16)((u + 0x7fffu + ((u >> 16) & 1u)) >> 16);   // RNE
}
__device__ __forceinline__ float bf2f(u16 h) {
  return __uint_as_float(((u32)h) << 16);
}
__device__ __forceinline__ u32 cvtpk(float lo, float hi) {   // T12: 1 instr vs ~8 VALU
  u32 r;
  asm("v_cvt_pk_bf16_f32 %0, %1, %2" : "=v"(r) : "v"(lo), "v"(hi));
  return r;
}
__device__ __forceinline__ void plswap(u32& a, u32& b) {     // lane halves swap
  asm volatile("v_permlane32_swap_b32 %0, %1" : "+v"(a), "+v"(b));
}
__device__ __forceinline__ void gload_lds16(const void* g, void* l) {
  __builtin_amdgcn_global_load_lds((const __attribute__((address_space(1))) void*)g,
                                   (__attribute__((address_space(3))) void*)l, 16, 0, 0);
}

// ---------------- f32 -> bf16 convert (vectorized, G13) ----------------
__global__ void __launch_bounds__(256) convert_x_kernel(const float* __restrict__ x,
                                                        u16* __restrict__ o) {
  int idx = (blockIdx.x * 256 + threadIdx.x) * 8;
  float4 a = *(const float4*)(x + idx);
  float4 b = *(const float4*)(x + idx + 4);
  union { u16 s[8]; uint4 v; } t;
  t.s[0] = f2bf(a.x); t.s[1] = f2bf(a.y); t.s[2] = f2bf(a.z); t.s[3] = f2bf(a.w);
  t.s[4] = f2bf(b.x); t.s[5] = f2bf(b.y); t.s[6] = f2bf(b.z); t.s[7] = f2bf(b.w);
  *(uint4*)(o + idx) = t.v;
}

// ------------- fused W transposes: z routes {Wq,Wk,Wv,Wo} -> bf16 W^T -------------
__global__ void __launch_bounds__(256) transpose_all_kernel(const float* __restrict__ Wq,
                                                            const float* __restrict__ Wk,
                                                            const float* __restrict__ Wv,
                                                            const float* __restrict__ Wo,
                                                            u16* __restrict__ wqkvt,
                                                            u16* __restrict__ wot) {
  const int z = blockIdx.z;
  const float* src = (z == 0) ? Wq : (z == 1) ? Wk : (z == 2) ? Wv : Wo;
  u16* dst = (z == 0) ? wqkvt
           : (z == 1) ? (wqkvt + (size_t)2048 * 2048)
           : (z == 2) ? (wqkvt + (size_t)2560 * 2048)
           : wot;
  const int N = (z == 1 || z == 2) ? 512 : 2048;
  if (blockIdx.y * 64 >= N) return;            // idle blocks for the narrow K/V mats
  __shared__ float t[64][65];
  const int bx = blockIdx.x, by = blockIdx.y, tid = threadIdx.x;
#pragma unroll
  for (int rep = 0; rep < 16; ++rep) {
    int lin = rep * 256 + tid;
    int i = lin >> 6, jj = lin & 63;                 // i = k-local, jj = n-local
    t[i][jj] = src[(size_t)(bx * 64 + i) * N + by * 64 + jj];
  }
  __syncthreads();
#pragma unroll
  for (int rep = 0; rep < 16; ++rep) {
    int lin = rep * 256 + tid;
    int nr = lin >> 6, kc = lin & 63;
    dst[(size_t)(by * 64 + nr) * DM + bx * 64 + kc] = f2bf(t[kc][nr]);
  }
}

// ------------- RoPE tables: ctab/stab[s*64 + i] -------------
__global__ void __launch_bounds__(256) rope_tables_kernel(float* __restrict__ ct,
                                                          float* __restrict__ st_) {
  int idx = blockIdx.x * 256 + threadIdx.x;          // 2048*64
  int s = idx >> 6, i = idx & 63;
  const float L2_10000 = 13.287712379549449f;
  float freq = exp2f(-(float)i * (1.0f / 64.0f) * L2_10000);
  float ang = (float)s * freq;
  ct[idx] = cosf(ang);
  st_[idx] = sinf(ang);
}

// ------------- GEMM: C[M][N] = A[M][K](bf16) * Bt[N][K](bf16)^T  (m97 structure) -------------
// T1: bijective XCD-aware block swizzle (m204) — consecutive swizzled ids share an XCD's L2.
template <int OUTF32>
__global__ void __launch_bounds__(256) gemm_bt(const u16* __restrict__ A,
                                               const u16* __restrict__ Bt,
                                               void* __restrict__ C,
                                               int M, int N, int K) {
  __shared__ __align__(16) u16 As[128 * 32];
  __shared__ __align__(16) u16 Bs[128 * 32];
  const int tid = threadIdx.x;
  const int w = tid >> 6, l = tid & 63;
  const int g = l >> 4, q15 = l & 15;

  // XCD swizzle (bijective for any nwg; m204 formula)
  const int nwg = gridDim.x * gridDim.y;
  int bid = blockIdx.y * gridDim.x + blockIdx.x;
  {
    int q = nwg >> 3, r = nwg & 7;
    int xcd = bid & 7, idx = bid >> 3;
    bid = (xcd < r ? xcd * (q + 1) : r * (q + 1) + (xcd - r) * q) + idx;
  }
  const int bx = bid % gridDim.x, by = bid / gridDim.x;
  const int row0 = by * 128, col0 = bx * 128;
  const int wm = (w >> 1) * 64, wn = (w & 1) * 64;
  const f32x4 fz = {0.f, 0.f, 0.f, 0.f};
  f32x4 acc[4][4];
#pragma unroll
  for (int m = 0; m < 4; ++m)
#pragma unroll
    for (int n = 0; n < 4; ++n) acc[m][n] = fz;

  for (int kt = 0; kt < K; kt += 32) {
#pragma unroll
    for (int c = 0; c < 2; ++c) {
      int P = (w * 2 + c) * 1024;
      int Pl = P + l * 16;
      int arow = Pl >> 6, acolb = Pl & 63;          // 64B per 32-elem row
      gload_lds16((const char*)A + ((size_t)(row0 + arow) * K + kt) * 2 + acolb,
                  (char*)As + P);
      gload_lds16((const char*)Bt + ((size_t)(col0 + arow) * K + kt) * 2 + acolb,
                  (char*)Bs + P);
    }
    __syncthreads();
    bf16x8 af[4], bfv[4];
#pragma unroll
    for (int m = 0; m < 4; ++m)
      af[m] = *(const bf16x8*)((const char*)As + (wm + m * 16 + q15) * 64 + g * 16);
#pragma unroll
    for (int n = 0; n < 4; ++n)
      bfv[n] = *(const bf16x8*)((const char*)Bs + (wn + n * 16 + q15) * 64 + g * 16);
#pragma unroll
    for (int m = 0; m < 4; ++m)
#pragma unroll
      for (int n = 0; n < 4; ++n)
        acc[m][n] = __builtin_amdgcn_mfma_f32_16x16x32_bf16(af[m], bfv[n], acc[m][n], 0, 0, 0);
    __syncthreads();
  }
#pragma unroll
  for (int m = 0; m < 4; ++m)
#pragma unroll
    for (int n = 0; n < 4; ++n)
#pragma unroll
      for (int r = 0; r < 4; ++r) {
        int rr = row0 + wm + m * 16 + g * 4 + r;    // C/D: row=(l>>4)*4+reg
        int cc = col0 + wn + n * 16 + q15;          //      col=l&15
        float v = acc[m][n][r];
        if (OUTF32) ((float*)C)[(size_t)rr * N + cc] = v;
        else        ((u16*)C)[(size_t)rr * N + cc]  = f2bf(v);
      }
}

// ------------- fused RMSNorm + RoPE; one wave per (row, head-job) -------------
// jobs 0..15 = q heads (pre-scaled by 1/sqrt(DH)), 16..19 = k heads
__global__ void __launch_bounds__(256) norm_rope_kernel(const u16* __restrict__ qkv,
                                                        const float* __restrict__ qw,
                                                        const float* __restrict__ kw,
                                                        const float* __restrict__ ct,
                                                        const float* __restrict__ st_,
                                                        u16* __restrict__ Qo,
                                                        u16* __restrict__ Ko) {
  int wid = blockIdx.x * 4 + (threadIdx.x >> 6);
  int l = threadIdx.x & 63;
  int row = wid / 20;
  int j = wid - row * 20;
  int b = row >> 11, s = row & 2047;
  bool isq = j < 16;
  int h = isq ? j : (j - 16);
  const u16* src = qkv + (size_t)row * QKV_N + (isq ? h * DH : (2048 + h * DH));
  float x1 = bf2f(src[l]), x2 = bf2f(src[l + 64]);
  float ss = x1 * x1 + x2 * x2;
#pragma unroll
  for (int off = 32; off > 0; off >>= 1) ss += __shfl_xor(ss, off);
  float rn = rsqrtf(ss * (1.0f / 128.0f) + 1e-6f);
  const float* wv = isq ? qw : kw;
  float n1 = x1 * rn * wv[l], n2 = x2 * rn * wv[l + 64];
  float cv = ct[s * 64 + l], sv = st_[s * 64 + l];
  float o1 = n1 * cv - n2 * sv;
  float o2 = n2 * cv + n1 * sv;
  float scale = isq ? 0.08838834764831845f : 1.0f;   // 1/sqrt(128) folded into Q
  u16* dst = isq ? (Qo + ((size_t)(b * NH + h) * S_LEN + s) * DH)
                 : (Ko + ((size_t)(b * NKV + h) * S_LEN + s) * DH);
  dst[l]      = f2bf(o1 * scale);
  dst[l + 64] = f2bf(o2 * scale);
}

// ------------- V transpose: qkv[...,2560+h*128+d] -> vt[(b*4+h)*128+d][S] -------------
__global__ void __launch_bounds__(256) vtrans_kernel(const u16* __restrict__ qkv,
                                                     u16* __restrict__ vt) {
  __shared__ u16 t[64][65];
  const int st = blockIdx.x, dt = blockIdx.y, bz = blockIdx.z;  // bz = b*4+h
  const int tid = threadIdx.x;
#pragma unroll
  for (int rep = 0; rep < 16; ++rep) {
    int lin = rep * 256 + tid;
    int i = lin >> 6, jj = lin & 63;                // i = s-local, jj = d-local
    t[i][jj] = qkv[(size_t)((bz >> 2) * S_LEN + st * 64 + i) * QKV_N
                   + 2560 + (bz & 3) * DH + dt * 64 + jj];
  }
  __syncthreads();
#pragma unroll
  for (int rep = 0; rep < 16; ++rep) {
    int lin = rep * 256 + tid;
    int dr = lin >> 6, sc = lin & 63;
    vt[((size_t)bz * DH + dt * 64 + dr) * S_LEN + st * 64 + sc] = t[sc][dr];
  }
}

// ------------- flash attention, 32x32 swapped-QK core (R9 verbatim — verified 78.9us) -------------
// 128 q-rows/block, 4 warps x 32 q-rows, KV tile 64. K+V dbuf in LDS (64KB).
// QK^T = mfma_32x32x16(K,Q): lane holds P[q=l&31][16 kv-rows] -> softmax reduce is
// in-lane + ONE shfl_xor(32). P -> PV B-frag via 16 cvt_pk + 8 permlane32_swap (VALU only).
// PV computes O^T = mfma(V^T, P^T): output col = q = l&31 -> alpha-rescale and 1/l epilogue
// are lane-local (zero shuffles). Defer-max (T13), setprio (T5).
// Swizzles (both-sides, rule 21): K rows 256B, XOR (row&15)<<4; V stored d-paired.
// Block id: bits [2:0]=(b,kvh) XCD-affine, [4:3]=q-head, [8:5]=LPT q-tile (longest first).
// R10-R12 lessons: perfect balance at 1 block/CU loses to R9 (TLP > balance); counted vmcnt
// is null here; split-K combine dies on device-fence L2 writebacks. R9 is the local optimum.
__global__ void __launch_bounds__(256, 2) attn_kernel(const u16* __restrict__ Qg,
                                                      const u16* __restrict__ Kg,
                                                      const u16* __restrict__ Vt,
                                                      u16* __restrict__ O) {
  __shared__ __align__(16) char smem[65536];   // [2][ K:16KB | V:16KB ]
  const int tid = threadIdx.x;
  const int w = tid >> 6, l = tid & 63;        // w = 0..3
  const int q31 = l & 31, hi = l >> 5;
  const int id = blockIdx.x;
  const int grp = id & 7;                      // b*4 + kvh
  const int mem = (id >> 3) & 3;               // q-head within kv group
  const int tq  = 15 - (id >> 5);              // LPT: longest first
  const int b   = grp >> 2, kvh = grp & 3;
  const int h   = kvh * 4 + mem;
  const int qb  = tq * 128;
  const int nkt = 2 * tq + 1;                  // last kv tile index
  const int qg  = qb + w * 32 + q31;           // lane's q row

  // Q row in registers: lane l&31 owns row qg; chunk c covers d = c*16 + hi*8 .. +7
  bf16x8 qreg[8];
  const u16* Qrow = Qg + ((size_t)(b * NH + h) * S_LEN + qg) * DH;
#pragma unroll
  for (int c = 0; c < 8; ++c)
    qreg[c] = *(const bf16x8*)(Qrow + c * 16 + hi * 8);

  const char* Kbase = (const char*)(Kg + (size_t)(b * NKV + kvh) * S_LEN * DH);
  const char* Vbase = (const char*)(Vt + (size_t)(b * NKV + kvh) * DH * S_LEN);

  // stage KV tile kt into buffer `buf` (linear LDS dest + inverse-swizzled global src)
  auto stage = [&](int buf, int kt) {
    char* Ksb = smem + buf * 32768;
    char* Vsb = Ksb + 16384;
    const char* Kt  = Kbase + (size_t)kt * 64 * 256;
    const char* Vtb = Vbase + (size_t)kt * 128;
#pragma unroll
    for (int i = 0; i < 4; ++i) {
      int off = w * 4096 + i * 1024 + l * 16;
      int row = off >> 8;
      { // K: [64 kv][128 d] bf16, rows 256B, XOR (row&15)<<4
        int cb = (off & 255) ^ ((row & 15) << 4);
        gload_lds16(Kt + (size_t)row * 256 + cb, Ksb + off); }
      { // V: d-paired rows: row=d>>1, byte7=d&1, low 7 bits = kv*2
        int qoff = (off & 255) ^ ((row & 15) << 4);
        int d = row * 2 + (qoff >> 7);
        int kvb = qoff & 127;
        gload_lds16(Vtb + (size_t)d * (S_LEN * 2) + kvb, Vsb + off); }
    }
  };

  f32x16 acc[4];
#pragma unroll
  for (int dt = 0; dt < 4; ++dt)
#pragma unroll
    for (int r = 0; r < 16; ++r) acc[dt][r] = 0.f;
  float mrun = -1e30f, lrun = 0.f;

  stage(0, 0);
  __syncthreads();
  int cur = 0;

  for (int kt = 0; kt <= nkt; ++kt) {
    if (kt < nkt) stage(cur ^ 1, kt + 1);     // prefetch next tile (overlaps compute)
    const char* Ks = smem + cur * 32768;
    const char* Vs = Ks + 16384;

    // QK^T swapped: sa[s] = K[s-subtile] * Q^T -> P^T tile [32 kv][32 q]
    // lane: q=l&31; reg r -> kv = s*32 + (r&3) + 8*(r>>2) + 4*hi
    f32x16 sa[2];
#pragma unroll
    for (int s = 0; s < 2; ++s)
#pragma unroll
      for (int r = 0; r < 16; ++r) sa[s][r] = 0.f;
    __builtin_amdgcn_s_setprio(1);
#pragma unroll
    for (int s = 0; s < 2; ++s) {
      int krow = s * 32 + q31;
      const char* kr = Ks + krow * 256;
      int sw = (krow & 15) << 4;
#pragma unroll
      for (int c = 0; c < 8; ++c) {
        bf16x8 kf = *(const bf16x8*)(kr + ((c * 32 + hi * 16) ^ sw));
        sa[s] = __builtin_amdgcn_mfma_f32_32x32x16_bf16(kf, qreg[c], sa[s], 0, 0, 0);
      }
    }
    __builtin_amdgcn_s_setprio(0);

    // masking + in-lane max (bound kt*64+63 vs warp base — R8 lesson)
    const bool domask = (kt * 64 + 63) > (qb + w * 32);
    float tmax = -1e30f;
#pragma unroll
    for (int s = 0; s < 2; ++s)
#pragma unroll
      for (int r = 0; r < 16; ++r) {
        float v = sa[s][r];
        if (domask) {
          int kvg = kt * 64 + s * 32 + (r & 3) + 8 * (r >> 2) + 4 * hi;
          if (kvg > qg) v = -1e30f;
        }
        sa[s][r] = v;
        tmax = fmaxf(tmax, v);
      }
    tmax = fmaxf(tmax, __shfl_xor(tmax, 32));

    const bool defer = __all(tmax <= mrun + 8.0f);  // T13 (wave-uniform)
    const float mnew = defer ? mrun : fmaxf(mrun, tmax);

    // exp + pack to PV B-frags: pfrag[ks] = P[q=l&31][kv = ks*16 + hi*8 + (0..7)]
    float tsum = 0.f;
    union { u32 u[4]; bf16x8 v; } pf[4];
#pragma unroll
    for (int s = 0; s < 2; ++s)
#pragma unroll
      for (int kl = 0; kl < 2; ++kl) {
        float e0 = __expf(sa[s][kl * 8 + 0] - mnew);
        float e1 = __expf(sa[s][kl * 8 + 1] - mnew);
        float e2 = __expf(sa[s][kl * 8 + 2] - mnew);
        float e3 = __expf(sa[s][kl * 8 + 3] - mnew);
        float e4 = __expf(sa[s][kl * 8 + 4] - mnew);
        float e5 = __expf(sa[s][kl * 8 + 5] - mnew);
        float e6 = __expf(sa[s][kl * 8 + 6] - mnew);
        float e7 = __expf(sa[s][kl * 8 + 7] - mnew);
        tsum += (e0 + e1) + (e2 + e3) + (e4 + e5) + (e6 + e7);
        u32 A0 = cvtpk(e0, e1), A1 = cvtpk(e2, e3);
        u32 B0 = cvtpk(e4, e5), B1 = cvtpk(e6, e7);
        plswap(A0, B0);   // -> word0 / word2
        plswap(A1, B1);   // -> word1 / word3
        int ks = s * 2 + kl;
        pf[ks].u[0] = A0; pf[ks].u[1] = A1; pf[ks].u[2] = B0; pf[ks].u[3] = B1;
      }
    tsum += __shfl_xor(tsum, 32);

    if (defer) {
      lrun += tsum;
    } else {
      float alpha = __expf(mrun - mnew);
      lrun = lrun * alpha + tsum;
      mrun = mnew;
#pragma unroll
      for (int dt = 0; dt < 4; ++dt)
#pragma unroll
        for (int r = 0; r < 16; ++r) acc[dt][r] *= alpha;   // lane-local (col = q)
    }

    // PV: acc[dt] += V^T-frag(dt,ks) * pfrag[ks]  -> O^T[d][q]
    __builtin_amdgcn_s_setprio(1);
#pragma unroll
    for (int dt = 0; dt < 4; ++dt) {
      int d = dt * 32 + q31;
      int vrow = d >> 1;
      const char* vr = Vs + vrow * 256;
      int sw = (vrow & 15) << 4;
      int hb = (d & 1) << 7;
#pragma unroll
      for (int ks = 0; ks < 4; ++ks) {
        bf16x8 vf = *(const bf16x8*)(vr + ((hb | (ks * 32 + hi * 16)) ^ sw));
        acc[dt] = __builtin_amdgcn_mfma_f32_32x32x16_bf16(vf, pf[ks].v, acc[dt], 0, 0, 0);
      }
    }
    __builtin_amdgcn_s_setprio(0);

    __syncthreads();   // drains prefetch (vmcnt 0) + guards buffer reuse
    cur ^= 1;
  }

  // epilogue: lane-local 1/l, pack pairs, 8B stores. acc[dt][r] = O[qg][dt*32+(r&3)+8*(r>>2)+4*hi]
  const float linv = 1.0f / lrun;
  u16* Obase = O + ((size_t)b * S_LEN + qg) * DM + h * DH;
#pragma unroll
  for (int dt = 0; dt < 4; ++dt)
#pragma unroll
    for (int rg = 0; rg < 4; ++rg) {
      int d0 = dt * 32 + rg * 8 + hi * 4;
      u32 w0 = cvtpk(acc[dt][rg * 4 + 0] * linv, acc[dt][rg * 4 + 1] * linv);
      u32 w1 = cvtpk(acc[dt][rg * 4 + 2] * linv, acc[dt][rg * 4 + 3] * linv);
      u64 vv = (u64)w0 | ((u64)w1 << 32);
      *(u64*)(Obase + d0) = vv;
    }
}

extern "C" void kernel_launch(void* const* d_in, const int* in_sizes, int n_in,
                              void* d_out, int out_size, void* d_ws, size_t ws_size,
                              hipStream_t stream) {
  (void)in_sizes; (void)n_in; (void)out_size; (void)ws_size;
  const float* x  = (const float*)d_in[0];
  const float* Wq = (const float*)d_in[1];
  const float* Wk = (const float*)d_in[2];
  const float* Wv = (const float*)d_in[3];
  const float* Wo = (const float*)d_in[4];
  const float* qw = (const float*)d_in[5];
  const float* kw = (const float*)d_in[6];

  char* ws = (char*)d_ws;
  // ws layout (~61 MB). attn_out aliases xb (xb dead after gemm1's A-read? no — after gemm0;
  // xb dead once gemm0 completes, attn writes land later).
  u16*   xb    = (u16*)(ws + 0);                       // 16.8 MB [4096][2048]
  u16*   wqkvt = (u16*)(ws + 16777216);                // 12.6 MB [3072][2048]
  u16*   wot   = (u16*)(ws + 29360128);                //  8.4 MB [2048][2048]
  u16*   qo    = (u16*)(ws + 37748736);                // 16.8 MB [B][16][S][128]
  u16*   ko    = (u16*)(ws + 54525952);                //  4.2 MB [B][4][S][128]
  u16*   vt    = (u16*)(ws + 58720256);                //  4.2 MB [B][4][128][S]
  float* ctab  = (float*)(ws + 62914560);              //  0.5 MB
  float* stab  = (float*)(ws + 63438848);              //  0.5 MB
  u16*   qkvp  = (u16*)d_out;                          // 25.2 MB staged in d_out
  u16*   attn  = (u16*)(ws + 0);                       // aliases xb
  float* outp  = (float*)d_out;

  convert_x_kernel<<<4096, 256, 0, stream>>>(x, xb);
  transpose_all_kernel<<<dim3(32, 32, 4), 256, 0, stream>>>(Wq, Wk, Wv, Wo, wqkvt, wot);
  rope_tables_kernel<<<512, 256, 0, stream>>>(ctab, stab);

  gemm_bt<0><<<dim3(24, 32), 256, 0, stream>>>(xb, wqkvt, qkvp, MROWS, QKV_N, DM);
  norm_rope_kernel<<<20480, 256, 0, stream>>>(qkvp, qw, kw, ctab, stab, qo, ko);
  vtrans_kernel<<<dim3(32, 2, 8), 256, 0, stream>>>(qkvp, vt);
  attn_kernel<<<512, 256, 0, stream>>>(qo, ko, vt, attn);
  gemm_bt<1><<<dim3(16, 32), 256, 0, stream>>>(attn, wot, outp, MROWS, DM, DM);
}

// Round 14
// 206.787 us; speedup vs baseline: 2.2755x; 1.1167x over previous
//
#include <hip/hip_runtime.h>
#include <stdint.h>

typedef __attribute__((ext_vector_type(8))) short bf16x8;
typedef __attribute__((ext_vector_type(4))) float f32x4;
typedef __attribute__((ext_vector_type(16))) float f32x16;
typedef unsigned short u16;
typedef unsigned int   u32;
typedef unsigned long long u64;

#define S_LEN 2048
#define NH    16
#define NKV   4
#define DH    128
#define DM    2048
#define QKV_N 3072
#define MROWS 4096   // B*S

__device__ __forceinline__ u16 f2bf(float x) {
  u32 u = __float_as_uint(x);
  return (u16)((u + 0x7fffu + ((u >> 16) & 1u)) >> 16);   // RNE
}
__device__ __forceinline__ float bf2f(u16 h) {
  return __uint_as_float(((u32)h) << 16);
}
__device__ __forceinline__ u32 cvtpk(float lo, float hi) {   // T12: 1 instr vs ~8 VALU
  u32 r;
  asm("v_cvt_pk_bf16_f32 %0, %1, %2" : "=v"(r) : "v"(lo), "v"(hi));
  return r;
}
__device__ __forceinline__ void plswap(u32& a, u32& b) {     // lane halves swap
  asm volatile("v_permlane32_swap_b32 %0, %1" : "+v"(a), "+v"(b));
}
__device__ __forceinline__ void gload_lds16(const void* g, void* l) {
  __builtin_amdgcn_global_load_lds((const __attribute__((address_space(1))) void*)g,
                                   (__attribute__((address_space(3))) void*)l, 16, 0, 0);
}

// ---------------- f32 -> bf16 convert (vectorized, G13) ----------------
__global__ void __launch_bounds__(256) convert_x_kernel(const float* __restrict__ x,
                                                        u16* __restrict__ o) {
  int idx = (blockIdx.x * 256 + threadIdx.x) * 8;
  float4 a = *(const float4*)(x + idx);
  float4 b = *(const float4*)(x + idx + 4);
  union { u16 s[8]; uint4 v; } t;
  t.s[0] = f2bf(a.x); t.s[1] = f2bf(a.y); t.s[2] = f2bf(a.z); t.s[3] = f2bf(a.w);
  t.s[4] = f2bf(b.x); t.s[5] = f2bf(b.y); t.s[6] = f2bf(b.z); t.s[7] = f2bf(b.w);
  *(uint4*)(o + idx) = t.v;
}

// ------------- fused W transposes: z routes {Wq,Wk,Wv,Wo} -> bf16 W^T -------------
__global__ void __launch_bounds__(256) transpose_all_kernel(const float* __restrict__ Wq,
                                                            const float* __restrict__ Wk,
                                                            const float* __restrict__ Wv,
                                                            const float* __restrict__ Wo,
                                                            u16* __restrict__ wqkvt,
                                                            u16* __restrict__ wot) {
  const int z = blockIdx.z;
  const float* src = (z == 0) ? Wq : (z == 1) ? Wk : (z == 2) ? Wv : Wo;
  u16* dst = (z == 0) ? wqkvt
           : (z == 1) ? (wqkvt + (size_t)2048 * 2048)
           : (z == 2) ? (wqkvt + (size_t)2560 * 2048)
           : wot;
  const int N = (z == 1 || z == 2) ? 512 : 2048;
  if (blockIdx.y * 64 >= N) return;            // idle blocks for the narrow K/V mats
  __shared__ float t[64][65];
  const int bx = blockIdx.x, by = blockIdx.y, tid = threadIdx.x;
#pragma unroll
  for (int rep = 0; rep < 16; ++rep) {
    int lin = rep * 256 + tid;
    int i = lin >> 6, jj = lin & 63;                 // i = k-local, jj = n-local
    t[i][jj] = src[(size_t)(bx * 64 + i) * N + by * 64 + jj];
  }
  __syncthreads();
#pragma unroll
  for (int rep = 0; rep < 16; ++rep) {
    int lin = rep * 256 + tid;
    int nr = lin >> 6, kc = lin & 63;
    dst[(size_t)(by * 64 + nr) * DM + bx * 64 + kc] = f2bf(t[kc][nr]);
  }
}

// ------------- RoPE tables: ctab/stab[s*64 + i] -------------
__global__ void __launch_bounds__(256) rope_tables_kernel(float* __restrict__ ct,
                                                          float* __restrict__ st_) {
  int idx = blockIdx.x * 256 + threadIdx.x;          // 2048*64
  int s = idx >> 6, i = idx & 63;
  const float L2_10000 = 13.287712379549449f;
  float freq = exp2f(-(float)i * (1.0f / 64.0f) * L2_10000);
  float ang = (float)s * freq;
  ct[idx] = cosf(ang);
  st_[idx] = sinf(ang);
}

// ------------- GEMM: C[M][N] = A[M][K](bf16) * Bt[N][K](bf16)^T -------------
// m97 structure + two fixes (R13 PMC: 6.29M LDS bank conflicts, 27% MfmaUtil):
//  (1) BK=64 (LDS 32KB, 4 blocks/CU) -> barrier drains halve.
//  (2) T2 XOR swizzle, both-sides (rule 21): LDS rows are 128B; reads at
//      row*128 + ((kk*64+g*16) ^ ((row&7)<<4)) -> 16 lanes hit 8 distinct 16B
//      slots = 2-way (free, m136). Staging keeps LINEAR LDS dest and applies the
//      inverse swizzle to the per-lane GLOBAL source (validated in attn: conflicts=0).
// T1: bijective XCD-aware block swizzle (m204).
template <int OUTF32>
__global__ void __launch_bounds__(256) gemm_bt(const u16* __restrict__ A,
                                               const u16* __restrict__ Bt,
                                               void* __restrict__ C,
                                               int M, int N, int K) {
  __shared__ __align__(16) u16 As[128 * 64];
  __shared__ __align__(16) u16 Bs[128 * 64];
  const int tid = threadIdx.x;
  const int w = tid >> 6, l = tid & 63;
  const int g = l >> 4, q15 = l & 15;

  // XCD swizzle (bijective for any nwg; m204 formula)
  const int nwg = gridDim.x * gridDim.y;
  int bid = blockIdx.y * gridDim.x + blockIdx.x;
  {
    int q = nwg >> 3, r = nwg & 7;
    int xcd = bid & 7, idx = bid >> 3;
    bid = (xcd < r ? xcd * (q + 1) : r * (q + 1) + (xcd - r) * q) + idx;
  }
  const int bx = bid % gridDim.x, by = bid / gridDim.x;
  const int row0 = by * 128, col0 = bx * 128;
  const int wm = (w >> 1) * 64, wn = (w & 1) * 64;
  const f32x4 fz = {0.f, 0.f, 0.f, 0.f};
  f32x4 acc[4][4];
#pragma unroll
  for (int m = 0; m < 4; ++m)
#pragma unroll
    for (int n = 0; n < 4; ++n) acc[m][n] = fz;

  for (int kt = 0; kt < K; kt += 64) {
#pragma unroll
    for (int rnd = 0; rnd < 4; ++rnd) {
      int Pl = rnd * 4096 + tid * 16;
      int arow = Pl >> 7, off = Pl & 127;
      int scol = off ^ ((arow & 7) << 4);           // inverse swizzle on global source
      gload_lds16((const char*)A + ((size_t)(row0 + arow) * K + kt) * 2 + scol,
                  (char*)As + Pl);
      gload_lds16((const char*)Bt + ((size_t)(col0 + arow) * K + kt) * 2 + scol,
                  (char*)Bs + Pl);
    }
    __syncthreads();
#pragma unroll
    for (int kk = 0; kk < 2; ++kk) {
      bf16x8 af[4], bfv[4];
#pragma unroll
      for (int m = 0; m < 4; ++m) {
        int row = wm + m * 16 + q15;
        af[m] = *(const bf16x8*)((const char*)As + row * 128
                                 + ((kk * 64 + g * 16) ^ ((row & 7) << 4)));
      }
#pragma unroll
      for (int n = 0; n < 4; ++n) {
        int row = wn + n * 16 + q15;
        bfv[n] = *(const bf16x8*)((const char*)Bs + row * 128
                                  + ((kk * 64 + g * 16) ^ ((row & 7) << 4)));
      }
#pragma unroll
      for (int m = 0; m < 4; ++m)
#pragma unroll
        for (int n = 0; n < 4; ++n)
          acc[m][n] = __builtin_amdgcn_mfma_f32_16x16x32_bf16(af[m], bfv[n], acc[m][n], 0, 0, 0);
    }
    __syncthreads();
  }
#pragma unroll
  for (int m = 0; m < 4; ++m)
#pragma unroll
    for (int n = 0; n < 4; ++n)
#pragma unroll
      for (int r = 0; r < 4; ++r) {
        int rr = row0 + wm + m * 16 + g * 4 + r;    // C/D: row=(l>>4)*4+reg
        int cc = col0 + wn + n * 16 + q15;          //      col=l&15
        float v = acc[m][n][r];
        if (OUTF32) ((float*)C)[(size_t)rr * N + cc] = v;
        else        ((u16*)C)[(size_t)rr * N + cc]  = f2bf(v);
      }
}

// ------------- fused RMSNorm + RoPE; one wave per (row, head-job) -------------
// jobs 0..15 = q heads (pre-scaled by 1/sqrt(DH)), 16..19 = k heads
__global__ void __launch_bounds__(256) norm_rope_kernel(const u16* __restrict__ qkv,
                                                        const float* __restrict__ qw,
                                                        const float* __restrict__ kw,
                                                        const float* __restrict__ ct,
                                                        const float* __restrict__ st_,
                                                        u16* __restrict__ Qo,
                                                        u16* __restrict__ Ko) {
  int wid = blockIdx.x * 4 + (threadIdx.x >> 6);
  int l = threadIdx.x & 63;
  int row = wid / 20;
  int j = wid - row * 20;
  int b = row >> 11, s = row & 2047;
  bool isq = j < 16;
  int h = isq ? j : (j - 16);
  const u16* src = qkv + (size_t)row * QKV_N + (isq ? h * DH : (2048 + h * DH));
  float x1 = bf2f(src[l]), x2 = bf2f(src[l + 64]);
  float ss = x1 * x1 + x2 * x2;
#pragma unroll
  for (int off = 32; off > 0; off >>= 1) ss += __shfl_xor(ss, off);
  float rn = rsqrtf(ss * (1.0f / 128.0f) + 1e-6f);
  const float* wv = isq ? qw : kw;
  float n1 = x1 * rn * wv[l], n2 = x2 * rn * wv[l + 64];
  float cv = ct[s * 64 + l], sv = st_[s * 64 + l];
  float o1 = n1 * cv - n2 * sv;
  float o2 = n2 * cv + n1 * sv;
  float scale = isq ? 0.08838834764831845f : 1.0f;   // 1/sqrt(128) folded into Q
  u16* dst = isq ? (Qo + ((size_t)(b * NH + h) * S_LEN + s) * DH)
                 : (Ko + ((size_t)(b * NKV + h) * S_LEN + s) * DH);
  dst[l]      = f2bf(o1 * scale);
  dst[l + 64] = f2bf(o2 * scale);
}

// ------------- V transpose: qkv[...,2560+h*128+d] -> vt[(b*4+h)*128+d][S] -------------
__global__ void __launch_bounds__(256) vtrans_kernel(const u16* __restrict__ qkv,
                                                     u16* __restrict__ vt) {
  __shared__ u16 t[64][65];
  const int st = blockIdx.x, dt = blockIdx.y, bz = blockIdx.z;  // bz = b*4+h
  const int tid = threadIdx.x;
#pragma unroll
  for (int rep = 0; rep < 16; ++rep) {
    int lin = rep * 256 + tid;
    int i = lin >> 6, jj = lin & 63;                // i = s-local, jj = d-local
    t[i][jj] = qkv[(size_t)((bz >> 2) * S_LEN + st * 64 + i) * QKV_N
                   + 2560 + (bz & 3) * DH + dt * 64 + jj];
  }
  __syncthreads();
#pragma unroll
  for (int rep = 0; rep < 16; ++rep) {
    int lin = rep * 256 + tid;
    int dr = lin >> 6, sc = lin & 63;
    vt[((size_t)bz * DH + dt * 64 + dr) * S_LEN + st * 64 + sc] = t[sc][dr];
  }
}

// ------------- flash attention, 32x32 swapped-QK core (R9 verbatim — verified 78.9us) -------------
// 128 q-rows/block, 4 warps x 32 q-rows, KV tile 64. K+V dbuf in LDS (64KB).
// QK^T = mfma_32x32x16(K,Q): lane holds P[q=l&31][16 kv-rows] -> softmax reduce is
// in-lane + ONE shfl_xor(32). P -> PV B-frag via 16 cvt_pk + 8 permlane32_swap (VALU only).
// PV computes O^T = mfma(V^T, P^T): output col = q = l&31 -> alpha-rescale and 1/l epilogue
// are lane-local (zero shuffles). Defer-max (T13), setprio (T5).
// Swizzles (both-sides, rule 21): K rows 256B, XOR (row&15)<<4; V stored d-paired.
// Block id: bits [2:0]=(b,kvh) XCD-affine, [4:3]=q-head, [8:5]=LPT q-tile (longest first).
// R10-R12 lessons: perfect balance at 1 block/CU loses to R9 (TLP > balance); counted vmcnt
// is null here; split-K combine dies on device-fence L2 writebacks. R9 is the local optimum.
__global__ void __launch_bounds__(256, 2) attn_kernel(const u16* __restrict__ Qg,
                                                      const u16* __restrict__ Kg,
                                                      const u16* __restrict__ Vt,
                                                      u16* __restrict__ O) {
  __shared__ __align__(16) char smem[65536];   // [2][ K:16KB | V:16KB ]
  const int tid = threadIdx.x;
  const int w = tid >> 6, l = tid & 63;        // w = 0..3
  const int q31 = l & 31, hi = l >> 5;
  const int id = blockIdx.x;
  const int grp = id & 7;                      // b*4 + kvh
  const int mem = (id >> 3) & 3;               // q-head within kv group
  const int tq  = 15 - (id >> 5);              // LPT: longest first
  const int b   = grp >> 2, kvh = grp & 3;
  const int h   = kvh * 4 + mem;
  const int qb  = tq * 128;
  const int nkt = 2 * tq + 1;                  // last kv tile index
  const int qg  = qb + w * 32 + q31;           // lane's q row

  // Q row in registers: lane l&31 owns row qg; chunk c covers d = c*16 + hi*8 .. +7
  bf16x8 qreg[8];
  const u16* Qrow = Qg + ((size_t)(b * NH + h) * S_LEN + qg) * DH;
#pragma unroll
  for (int c = 0; c < 8; ++c)
    qreg[c] = *(const bf16x8*)(Qrow + c * 16 + hi * 8);

  const char* Kbase = (const char*)(Kg + (size_t)(b * NKV + kvh) * S_LEN * DH);
  const char* Vbase = (const char*)(Vt + (size_t)(b * NKV + kvh) * DH * S_LEN);

  // stage KV tile kt into buffer `buf` (linear LDS dest + inverse-swizzled global src)
  auto stage = [&](int buf, int kt) {
    char* Ksb = smem + buf * 32768;
    char* Vsb = Ksb + 16384;
    const char* Kt  = Kbase + (size_t)kt * 64 * 256;
    const char* Vtb = Vbase + (size_t)kt * 128;
#pragma unroll
    for (int i = 0; i < 4; ++i) {
      int off = w * 4096 + i * 1024 + l * 16;
      int row = off >> 8;
      { // K: [64 kv][128 d] bf16, rows 256B, XOR (row&15)<<4
        int cb = (off & 255) ^ ((row & 15) << 4);
        gload_lds16(Kt + (size_t)row * 256 + cb, Ksb + off); }
      { // V: d-paired rows: row=d>>1, byte7=d&1, low 7 bits = kv*2
        int qoff = (off & 255) ^ ((row & 15) << 4);
        int d = row * 2 + (qoff >> 7);
        int kvb = qoff & 127;
        gload_lds16(Vtb + (size_t)d * (S_LEN * 2) + kvb, Vsb + off); }
    }
  };

  f32x16 acc[4];
#pragma unroll
  for (int dt = 0; dt < 4; ++dt)
#pragma unroll
    for (int r = 0; r < 16; ++r) acc[dt][r] = 0.f;
  float mrun = -1e30f, lrun = 0.f;

  stage(0, 0);
  __syncthreads();
  int cur = 0;

  for (int kt = 0; kt <= nkt; ++kt) {
    if (kt < nkt) stage(cur ^ 1, kt + 1);     // prefetch next tile (overlaps compute)
    const char* Ks = smem + cur * 32768;
    const char* Vs = Ks + 16384;

    // QK^T swapped: sa[s] = K[s-subtile] * Q^T -> P^T tile [32 kv][32 q]
    // lane: q=l&31; reg r -> kv = s*32 + (r&3) + 8*(r>>2) + 4*hi
    f32x16 sa[2];
#pragma unroll
    for (int s = 0; s < 2; ++s)
#pragma unroll
      for (int r = 0; r < 16; ++r) sa[s][r] = 0.f;
    __builtin_amdgcn_s_setprio(1);
#pragma unroll
    for (int s = 0; s < 2; ++s) {
      int krow = s * 32 + q31;
      const char* kr = Ks + krow * 256;
      int sw = (krow & 15) << 4;
#pragma unroll
      for (int c = 0; c < 8; ++c) {
        bf16x8 kf = *(const bf16x8*)(kr + ((c * 32 + hi * 16) ^ sw));
        sa[s] = __builtin_amdgcn_mfma_f32_32x32x16_bf16(kf, qreg[c], sa[s], 0, 0, 0);
      }
    }
    __builtin_amdgcn_s_setprio(0);

    // masking + in-lane max (bound kt*64+63 vs warp base — R8 lesson)
    const bool domask = (kt * 64 + 63) > (qb + w * 32);
    float tmax = -1e30f;
#pragma unroll
    for (int s = 0; s < 2; ++s)
#pragma unroll
      for (int r = 0; r < 16; ++r) {
        float v = sa[s][r];
        if (domask) {
          int kvg = kt * 64 + s * 32 + (r & 3) + 8 * (r >> 2) + 4 * hi;
          if (kvg > qg) v = -1e30f;
        }
        sa[s][r] = v;
        tmax = fmaxf(tmax, v);
      }
    tmax = fmaxf(tmax, __shfl_xor(tmax, 32));

    const bool defer = __all(tmax <= mrun + 8.0f);  // T13 (wave-uniform)
    const float mnew = defer ? mrun : fmaxf(mrun, tmax);

    // exp + pack to PV B-frags: pfrag[ks] = P[q=l&31][kv = ks*16 + hi*8 + (0..7)]
    float tsum = 0.f;
    union { u32 u[4]; bf16x8 v; } pf[4];
#pragma unroll
    for (int s = 0; s < 2; ++s)
#pragma unroll
      for (int kl = 0; kl < 2; ++kl) {
        float e0 = __expf(sa[s][kl * 8 + 0] - mnew);
        float e1 = __expf(sa[s][kl * 8 + 1] - mnew);
        float e2 = __expf(sa[s][kl * 8 + 2] - mnew);
        float e3 = __expf(sa[s][kl * 8 + 3] - mnew);
        float e4 = __expf(sa[s][kl * 8 + 4] - mnew);
        float e5 = __expf(sa[s][kl * 8 + 5] - mnew);
        float e6 = __expf(sa[s][kl * 8 + 6] - mnew);
        float e7 = __expf(sa[s][kl * 8 + 7] - mnew);
        tsum += (e0 + e1) + (e2 + e3) + (e4 + e5) + (e6 + e7);
        u32 A0 = cvtpk(e0, e1), A1 = cvtpk(e2, e3);
        u32 B0 = cvtpk(e4, e5), B1 = cvtpk(e6, e7);
        plswap(A0, B0);   // -> word0 / word2
        plswap(A1, B1);   // -> word1 / word3
        int ks = s * 2 + kl;
        pf[ks].u[0] = A0; pf[ks].u[1] = A1; pf[ks].u[2] = B0; pf[ks].u[3] = B1;
      }
    tsum += __shfl_xor(tsum, 32);

    if (defer) {
      lrun += tsum;
    } else {
      float alpha = __expf(mrun - mnew);
      lrun = lrun * alpha + tsum;
      mrun = mnew;
#pragma unroll
      for (int dt = 0; dt < 4; ++dt)
#pragma unroll
        for (int r = 0; r < 16; ++r) acc[dt][r] *= alpha;   // lane-local (col = q)
    }

    // PV: acc[dt] += V^T-frag(dt,ks) * pfrag[ks]  -> O^T[d][q]
    __builtin_amdgcn_s_setprio(1);
#pragma unroll
    for (int dt = 0; dt < 4; ++dt) {
      int d = dt * 32 + q31;
      int vrow = d >> 1;
      const char* vr = Vs + vrow * 256;
      int sw = (vrow & 15) << 4;
      int hb = (d & 1) << 7;
#pragma unroll
      for (int ks = 0; ks < 4; ++ks) {
        bf16x8 vf = *(const bf16x8*)(vr + ((hb | (ks * 32 + hi * 16)) ^ sw));
        acc[dt] = __builtin_amdgcn_mfma_f32_32x32x16_bf16(vf, pf[ks].v, acc[dt], 0, 0, 0);
      }
    }
    __builtin_amdgcn_s_setprio(0);

    __syncthreads();   // drains prefetch (vmcnt 0) + guards buffer reuse
    cur ^= 1;
  }

  // epilogue: lane-local 1/l, pack pairs, 8B stores. acc[dt][r] = O[qg][dt*32+(r&3)+8*(r>>2)+4*hi]
  const float linv = 1.0f / lrun;
  u16* Obase = O + ((size_t)b * S_LEN + qg) * DM + h * DH;
#pragma unroll
  for (int dt = 0; dt < 4; ++dt)
#pragma unroll
    for (int rg = 0; rg < 4; ++rg) {
      int d0 = dt * 32 + rg * 8 + hi * 4;
      u32 w0 = cvtpk(acc[dt][rg * 4 + 0] * linv, acc[dt][rg * 4 + 1] * linv);
      u32 w1 = cvtpk(acc[dt][rg * 4 + 2] * linv, acc[dt][rg * 4 + 3] * linv);
      u64 vv = (u64)w0 | ((u64)w1 << 32);
      *(u64*)(Obase + d0) = vv;
    }
}

extern "C" void kernel_launch(void* const* d_in, const int* in_sizes, int n_in,
                              void* d_out, int out_size, void* d_ws, size_t ws_size,
                              hipStream_t stream) {
  (void)in_sizes; (void)n_in; (void)out_size; (void)ws_size;
  const float* x  = (const float*)d_in[0];
  const float* Wq = (const float*)d_in[1];
  const float* Wk = (const float*)d_in[2];
  const float* Wv = (const float*)d_in[3];
  const float* Wo = (const float*)d_in[4];
  const float* qw = (const float*)d_in[5];
  const float* kw = (const float*)d_in[6];

  char* ws = (char*)d_ws;
  // ws layout (~61 MB). attn_out aliases xb (xb dead after gemm0).
  u16*   xb    = (u16*)(ws + 0);                       // 16.8 MB [4096][2048]
  u16*   wqkvt = (u16*)(ws + 16777216);                // 12.6 MB [3072][2048]
  u16*   wot   = (u16*)(ws + 29360128);                //  8.4 MB [2048][2048]
  u16*   qo    = (u16*)(ws + 37748736);                // 16.8 MB [B][16][S][128]
  u16*   ko    = (u16*)(ws + 54525952);                //  4.2 MB [B][4][S][128]
  u16*   vt    = (u16*)(ws + 58720256);                //  4.2 MB [B][4][128][S]
  float* ctab  = (float*)(ws + 62914560);              //  0.5 MB
  float* stab  = (float*)(ws + 63438848);              //  0.5 MB
  u16*   qkvp  = (u16*)d_out;                          // 25.2 MB staged in d_out
  u16*   attn  = (u16*)(ws + 0);                       // aliases xb
  float* outp  = (float*)d_out;

  convert_x_kernel<<<4096, 256, 0, stream>>>(x, xb);
  transpose_all_kernel<<<dim3(32, 32, 4), 256, 0, stream>>>(Wq, Wk, Wv, Wo, wqkvt, wot);
  rope_tables_kernel<<<512, 256, 0, stream>>>(ctab, stab);

  gemm_bt<0><<<dim3(24, 32), 256, 0, stream>>>(xb, wqkvt, qkvp, MROWS, QKV_N, DM);
  norm_rope_kernel<<<20480, 256, 0, stream>>>(qkvp, qw, kw, ctab, stab, qo, ko);
  vtrans_kernel<<<dim3(32, 2, 8), 256, 0, stream>>>(qkvp, vt);
  attn_kernel<<<512, 256, 0, stream>>>(qo, ko, vt, attn);
  gemm_bt<1><<<dim3(16, 32), 256, 0, stream>>>(attn, wot, outp, MROWS, DM, DM);
}